// Round 2
// baseline (3305.217 us; speedup 1.0000x reference)
//
#include <hip/hip_runtime.h>
#include <hip/hip_bf16.h>
#include <hip/hip_cooperative_groups.h>
#include <float.h>

namespace cg = cooperative_groups;

#define F_DIM 64
#define H_DIM 128
#define K2    96       // padded K for [x[e0] | ppf]: 3 mfma K-steps of 32
#define LROW2 104      // bf16 row stride: 52 dwords, 52%32=20 -> <=2-way bank alias (free)
#define MT    64       // edge rows per MFMA tile

typedef __attribute__((ext_vector_type(8))) short short8;   // 8 bf16 (mfma A/B frag)
typedef __attribute__((ext_vector_type(4))) float f32x4;    // mfma C/D frag

__device__ __forceinline__ unsigned short f2bf(float f) {
    __hip_bfloat16 h = __float2bfloat16(f);
    return __builtin_bit_cast(unsigned short, h);
}
__device__ __forceinline__ float bf2f(unsigned short u) {
    unsigned v = (unsigned)u << 16;
    return __builtin_bit_cast(float, v);
}
__device__ __forceinline__ unsigned pk(float a, float b) {
    return (unsigned)f2bf(a) | ((unsigned)f2bf(b) << 16);
}

__device__ __forceinline__ float angle3(float ax, float ay, float az,
                                        float bx, float by, float bz) {
    float cx = ay*bz - az*by;
    float cy = az*bx - ax*bz;
    float cz = ax*by - ay*bx;
    float cn = sqrtf(cx*cx + cy*cy + cz*cz);
    float d  = ax*bx + ay*by + az*bz;
    return atan2f(cn, d);
}

// ONE cooperative kernel: weight transposes + node2slot + cnt-zero | hist | alloc | scatter
__global__ void prep_kernel(const float* __restrict__ W, unsigned short* __restrict__ wt2,
                            unsigned short* __restrict__ w1, const int* __restrict__ idx,
                            int* __restrict__ node2slot, const int* __restrict__ edge,
                            int* __restrict__ eslot, int* __restrict__ cnt,
                            int* __restrict__ off, int* __restrict__ cur,
                            int* __restrict__ perm, int S, int E) {
    __shared__ int wsum[4];
    __shared__ int bb;
    cg::grid_group grid = cg::this_grid();
    const int gsz = gridDim.x * blockDim.x;
    const int gid = blockIdx.x * blockDim.x + threadIdx.x;

    // P0a: wt2 [H][LROW2] <- W rows 64..131 ([x[e0]|ppf] part), zero-padded
    for (int g = gid; g < H_DIM * LROW2; g += gsz) {
        int h = g / LROW2, k = g % LROW2;
        float v = 0.f;
        if (k < F_DIM)          v = W[(F_DIM + k) * H_DIM + h];
        else if (k < F_DIM + 4) v = W[(2 * F_DIM + (k - F_DIM)) * H_DIM + h];
        wt2[h * LROW2 + k] = f2bf(v);
    }
    // P0b: w1 [H][64] <- W rows 0..63 (x[e1] part, for the per-segment constant)
    for (int g = gid; g < H_DIM * F_DIM; g += gsz) {
        int h = g >> 6, k = g & 63;
        w1[h * F_DIM + k] = f2bf(W[k * H_DIM + h]);
    }
    // P0c: canonical slot map + histogram zero (cnt[S] doubles as total-counter)
    for (int s = gid; s < S; s += gsz) node2slot[idx[s]] = s;
    for (int s = gid; s <= S; s += gsz) cnt[s] = 0;
    grid.sync();

    // P1: histogram (every e1 is a sampled node -> node2slot hit guaranteed)
    for (int e = gid; e < E; e += gsz) {
        int s = node2slot[edge[E + e]];
        eslot[e] = s;
        atomicAdd(&cnt[s], 1);
    }
    grid.sync();

    // P2: per-slot contiguous range alloc (order across slots irrelevant)
    int nch = (S + 255) >> 8;
    for (int c = blockIdx.x; c < nch; c += gridDim.x) {
        int s = c * 256 + threadIdx.x;
        int v = (s < S) ? cnt[s] : 0;
        int lane = threadIdx.x & 63, wv = threadIdx.x >> 6;
        int sc = v;
        #pragma unroll
        for (int d = 1; d < 64; d <<= 1) {
            int t = __shfl_up(sc, d, 64);
            if (lane >= d) sc += t;
        }
        if (lane == 63) wsum[wv] = sc;
        __syncthreads();
        if (threadIdx.x == 0) {
            int t = 0;
            #pragma unroll
            for (int i = 0; i < 4; ++i) { int w = wsum[i]; wsum[i] = t; t += w; }
            bb = atomicAdd(&cnt[S], t);
        }
        __syncthreads();
        int excl = bb + wsum[wv] + sc - v;
        if (s < S) { off[s] = excl; cur[s] = excl; }
        __syncthreads();   // wsum/bb reused next chunk
    }
    grid.sync();

    // P3: scatter edge ids to segment-contiguous perm
    for (int e = gid; e < E; e += gsz) {
        int p = atomicAdd(&cur[eslot[e]], 1);
        perm[p] = e;
    }
}

// one block per segment; K=96 MFMA over [x[e0]|ppf]; per-segment x[e1].W1+b added after max
__global__ __launch_bounds__(256, 4)
void seg_kernel(const float* __restrict__ x, const float* __restrict__ pos,
                const float* __restrict__ normal, const unsigned short* __restrict__ wt2,
                const unsigned short* __restrict__ w1, const float* __restrict__ bias,
                const int* __restrict__ edge, const int* __restrict__ idx,
                const int* __restrict__ perm, const int* __restrict__ off,
                const int* __restrict__ cnt, float* __restrict__ out, int E) {
    __shared__ __align__(16) unsigned short a_lds[MT * LROW2];
    __shared__ float x1_lds[F_DIM];
    __shared__ float pn_lds[6];

    const int s    = blockIdx.x;
    const int n    = cnt[s];
    const int tid  = threadIdx.x;
    const int wv   = tid >> 6;
    const int lane = tid & 63;
    const int l15  = lane & 15;
    const int quad = lane >> 4;
    const int n0 = wv * 32 + l15;
    const int n1 = n0 + 16;

    if (n == 0) {                       // empty segment (or non-canonical duplicate slot)
        if (quad == 0) {
            out[(size_t)s * H_DIM + n0] = 0.f;
            out[(size_t)s * H_DIM + n1] = 0.f;
        }
        return;
    }

    const int base = off[s];
    const int node = idx[s];            // n>0 => s is the canonical slot of idx[s]

    if (tid < F_DIM)                x1_lds[tid] = x[(size_t)node * F_DIM + tid];
    else if (tid < F_DIM + 3)       pn_lds[tid - F_DIM] = pos[(size_t)node * 3 + (tid - F_DIM)];
    else if (tid < F_DIM + 6)       pn_lds[tid - F_DIM] = normal[(size_t)node * 3 + (tid - F_DIM - 3)];

    // zero k=68..103 of every A row once (constant across chunks)
    const int m_row = tid >> 2;         // 0..63
    const int p4i   = tid & 3;
    {
        unsigned short* arow = a_lds + m_row * LROW2;
        uint4 z4 = make_uint4(0, 0, 0, 0);
        if (p4i == 0) { *(uint2*)(arow + 68) = make_uint2(0, 0); *(uint4*)(arow + 96) = z4; }
        else          { *(uint4*)(arow + 72 + (p4i - 1) * 8) = z4; }
    }
    __syncthreads();

    // per-segment constant c[h] = bias[h] + x[e1] . W1[:,h]  (f32 x, bf16 W as in MFMA)
    float c0 = bias[n0], c1 = bias[n1];
    {
        const short8* r0 = (const short8*)(w1 + (size_t)n0 * F_DIM);
        const short8* r1 = (const short8*)(w1 + (size_t)n1 * F_DIM);
        #pragma unroll
        for (int kk = 0; kk < 8; ++kk) {
            short8 a0 = r0[kk], a1 = r1[kk];
            #pragma unroll
            for (int j = 0; j < 8; ++j) {
                float xv = x1_lds[kk * 8 + j];
                c0 += xv * bf2f((unsigned short)a0[j]);
                c1 += xv * bf2f((unsigned short)a1[j]);
            }
        }
    }
    const float pe1x = pn_lds[0], pe1y = pn_lds[1], pe1z = pn_lds[2];
    const float ne1x = pn_lds[3], ne1y = pn_lds[4], ne1z = pn_lds[5];

    float rm0 = -FLT_MAX, rm1 = -FLT_MAX;

    for (int cbase = 0; cbase < n; cbase += MT) {
        int valid = n - cbase; if (valid > MT) valid = MT;
        int ntile = (valid + 15) >> 4;

        if (wv < ntile) {               // wave w stages rows [w*16, w*16+16) only
            int r = cbase + m_row;
            int e = perm[base + (r < n ? r : 0)];   // pad rows duplicate a real edge
            int e0 = edge[e];
            unsigned short* arow = a_lds + m_row * LROW2;
            // x[e0] quarter p4i: 16 feats -> 16 bf16
            const float4* s4 = (const float4*)(x + (size_t)e0 * F_DIM + p4i * 16);
            float4 f0 = s4[0], f1 = s4[1], f2 = s4[2], f3 = s4[3];
            uint4 q0, q1;
            q0.x = pk(f0.x, f0.y); q0.y = pk(f0.z, f0.w);
            q0.z = pk(f1.x, f1.y); q0.w = pk(f1.z, f1.w);
            q1.x = pk(f2.x, f2.y); q1.y = pk(f2.z, f2.w);
            q1.z = pk(f3.x, f3.y); q1.w = pk(f3.z, f3.w);
            *(uint4*)(arow + p4i * 16)     = q0;
            *(uint4*)(arow + p4i * 16 + 8) = q1;
            // ppf component p4i for this row
            float px = pos[3 * e0]     - pe1x;
            float py = pos[3 * e0 + 1] - pe1y;
            float pz = pos[3 * e0 + 2] - pe1z;
            float val;
            if (p4i == 0) {
                val = sqrtf(px * px + py * py + pz * pz);
            } else if (p4i == 1) {
                val = angle3(ne1x, ne1y, ne1z, px, py, pz);
            } else {
                float n0x = normal[3 * e0], n0y = normal[3 * e0 + 1], n0z = normal[3 * e0 + 2];
                val = (p4i == 2) ? angle3(n0x, n0y, n0z, px, py, pz)
                                 : angle3(ne1x, ne1y, ne1z, n0x, n0y, n0z);
            }
            arow[F_DIM + p4i] = f2bf(val);
        }
        __syncthreads();

        f32x4 acc[4][2];
        #pragma unroll
        for (int i = 0; i < 4; ++i) {
            acc[i][0] = (f32x4){0.f, 0.f, 0.f, 0.f};
            acc[i][1] = (f32x4){0.f, 0.f, 0.f, 0.f};
        }
        #pragma unroll
        for (int ks = 0; ks < 3; ++ks) {
            const int ko = ks * 32 + quad * 8;
            short8 bf0 = *(const short8*)(wt2 + (size_t)n0 * LROW2 + ko);
            short8 bf1 = *(const short8*)(wt2 + (size_t)n1 * LROW2 + ko);
            #pragma unroll
            for (int mt = 0; mt < 4; ++mt) {
                if (mt < ntile) {       // static acc index, runtime predicate
                    short8 af = *(const short8*)(a_lds + (mt * 16 + l15) * LROW2 + ko);
                    acc[mt][0] = __builtin_amdgcn_mfma_f32_16x16x32_bf16(af, bf0, acc[mt][0], 0, 0, 0);
                    acc[mt][1] = __builtin_amdgcn_mfma_f32_16x16x32_bf16(af, bf1, acc[mt][1], 0, 0, 0);
                }
            }
        }
        #pragma unroll
        for (int mt = 0; mt < 4; ++mt) {
            #pragma unroll
            for (int r = 0; r < 4; ++r) {
                int m = mt * 16 + quad * 4 + r;     // C/D layout: row = quad*4 + reg
                if (m < valid) {
                    rm0 = fmaxf(rm0, acc[mt][0][r]);
                    rm1 = fmaxf(rm1, acc[mt][1][r]);
                }
            }
        }
        __syncthreads();                // a_lds reused next chunk
    }

    // cross-quad max, then add constant and relu (relu is monotone => hoist is exact)
    rm0 = fmaxf(rm0, __shfl_xor(rm0, 16, 64));
    rm0 = fmaxf(rm0, __shfl_xor(rm0, 32, 64));
    rm1 = fmaxf(rm1, __shfl_xor(rm1, 16, 64));
    rm1 = fmaxf(rm1, __shfl_xor(rm1, 32, 64));
    if (quad == 0) {
        out[(size_t)s * H_DIM + n0] = fmaxf(c0 + rm0, 0.f);
        out[(size_t)s * H_DIM + n1] = fmaxf(c1 + rm1, 0.f);
    }
}

// duplicate-idx fixup (non-canonical rows copy from canonical) + pos gather
__global__ void finalize(const int* __restrict__ idx, const int* __restrict__ node2slot,
                         const float* __restrict__ pos, float* __restrict__ out, int S) {
    int g = blockIdx.x * blockDim.x + threadIdx.x;
    int total = S * H_DIM;
    if (g < total) {
        int s = g >> 7, c = g & 127;
        int node = idx[s];
        int sp = node2slot[node];
        if (sp != s) out[g] = out[(size_t)sp * H_DIM + c];
    } else if (g < total + 3 * S) {
        int g2 = g - total;
        int s = g2 / 3, j = g2 - 3 * s;
        out[total + g2] = pos[(size_t)idx[s] * 3 + j];
    }
}

extern "C" void kernel_launch(void* const* d_in, const int* in_sizes, int n_in,
                              void* d_out, int out_size, void* d_ws, size_t ws_size,
                              hipStream_t stream) {
    const float* x      = (const float*)d_in[0];
    const float* pos    = (const float*)d_in[1];
    const float* normal = (const float*)d_in[2];
    const float* W      = (const float*)d_in[3];
    const float* b      = (const float*)d_in[4];
    const int*   edge   = (const int*)d_in[5];
    const int*   idx    = (const int*)d_in[6];

    const int H = in_sizes[4];            // 128
    const int K = in_sizes[3] / H;        // 132
    const int F = (K - 4) / 2;            // 64
    const int N = in_sizes[0] / F;        // 100000
    const int E = in_sizes[5] / 2;        // 800000
    const int S = in_sizes[6];            // 25000

    // ws layout (256B aligned): wt2 | w1 | node2slot[N] | eslot[E] | perm[E] | cnt[S+1] | off[S] | cur[S]
    char* p = (char*)d_ws;
    auto alloc = [&](size_t bytes) { char* r = p; p += (bytes + 255) & ~(size_t)255; return r; };
    unsigned short* wt2 = (unsigned short*)alloc((size_t)H_DIM * LROW2 * sizeof(unsigned short));
    unsigned short* w1  = (unsigned short*)alloc((size_t)H_DIM * F_DIM * sizeof(unsigned short));
    int* node2slot      = (int*)alloc((size_t)N * sizeof(int));
    int* eslot          = (int*)alloc((size_t)E * sizeof(int));
    int* perm           = (int*)alloc((size_t)E * sizeof(int));
    int* cnt            = (int*)alloc((size_t)(S + 1) * sizeof(int));
    int* off            = (int*)alloc((size_t)S * sizeof(int));
    int* cur            = (int*)alloc((size_t)S * sizeof(int));
    float* out = (float*)d_out;

    int S_ = S, E_ = E;
    void* args[] = { (void*)&W, (void*)&wt2, (void*)&w1, (void*)&idx, (void*)&node2slot,
                     (void*)&edge, (void*)&eslot, (void*)&cnt, (void*)&off, (void*)&cur,
                     (void*)&perm, (void*)&S_, (void*)&E_ };
    hipLaunchCooperativeKernel((void*)prep_kernel, dim3(1024), dim3(256), args, 0, stream);
    seg_kernel<<<S, 256, 0, stream>>>(x, pos, normal, wt2, w1, b, edge, idx, perm, off, cnt, out, E);
    finalize<<<(S * H + 3 * S + 255) / 256, 256, 0, stream>>>(idx, node2slot, pos, out, S);
}

// Round 3
// 558.065 us; speedup vs baseline: 5.9226x; 5.9226x over previous
//
#include <hip/hip_runtime.h>
#include <hip/hip_bf16.h>
#include <float.h>

#define F_DIM 64
#define H_DIM 128
#define LROW2 104      // bf16 row stride for [x[e0]|ppf|pad]: 52 dwords -> <=2-way bank alias (free)
#define MT    64       // max edge rows per chunk

typedef __attribute__((ext_vector_type(8))) short short8;   // 8 bf16 (mfma A/B frag)
typedef __attribute__((ext_vector_type(4))) float f32x4;    // mfma C/D frag

__device__ __forceinline__ unsigned short f2bf(float f) {
    __hip_bfloat16 h = __float2bfloat16(f);
    return __builtin_bit_cast(unsigned short, h);
}
__device__ __forceinline__ float bf2f(unsigned short u) {
    unsigned v = (unsigned)u << 16;
    return __builtin_bit_cast(float, v);
}
__device__ __forceinline__ unsigned pk(float a, float b) {
    return (unsigned)f2bf(a) | ((unsigned)f2bf(b) << 16);
}

__device__ __forceinline__ float angle3(float ax, float ay, float az,
                                        float bx, float by, float bz) {
    float cx = ay*bz - az*by;
    float cy = az*bx - ax*bz;
    float cz = ax*by - ay*bx;
    float cn = sqrtf(cx*cx + cy*cy + cz*cz);
    float d  = ax*bx + ay*by + az*bz;
    return atan2f(cn, d);
}

// wt2 [H][LROW2] <- W rows 64..131 (the [x[e0]|ppf] block, zero-padded to 96+pad)
// w1  [H][64]    <- W rows 0..63  (x[e1] block, for the per-segment constant)
__global__ void build_w(const float* __restrict__ W, unsigned short* __restrict__ wt2,
                        unsigned short* __restrict__ w1) {
    int g = blockIdx.x * blockDim.x + threadIdx.x;
    if (g < H_DIM * LROW2) {
        int h = g / LROW2, k = g % LROW2;
        float v = 0.f;
        if (k < F_DIM)          v = W[(F_DIM + k) * H_DIM + h];
        else if (k < F_DIM + 4) v = W[(2 * F_DIM + (k - F_DIM)) * H_DIM + h];
        wt2[h * LROW2 + k] = f2bf(v);
    } else if (g < H_DIM * (LROW2 + F_DIM)) {
        int g2 = g - H_DIM * LROW2;
        int h = g2 >> 6, k = g2 & 63;
        w1[h * F_DIM + k] = f2bf(W[k * H_DIM + h]);
    }
}

__global__ void scatter_slots(const int* __restrict__ idx, int* __restrict__ node2slot, int S) {
    int s = blockIdx.x * blockDim.x + threadIdx.x;
    if (s < S) node2slot[idx[s]] = s;   // duplicate idx: any winner is the canonical slot
}

__global__ void hist_kernel(const int* __restrict__ edge, const int* __restrict__ node2slot,
                            int* __restrict__ eslot, int* __restrict__ cnt, int E) {
    int e = blockIdx.x * blockDim.x + threadIdx.x;
    if (e >= E) return;
    int s = node2slot[edge[E + e]];     // every e1 is a sampled node -> guaranteed hit
    eslot[e] = s;
    atomicAdd(&cnt[s], 1);
}

// per-slot contiguous range alloc (order across slots irrelevant)
__global__ void alloc_kernel(const int* __restrict__ cnt, int* __restrict__ off,
                             int* __restrict__ cur, int* __restrict__ total, int S) {
    __shared__ int wsum[4];
    __shared__ int bb;
    int s = blockIdx.x * 256 + threadIdx.x;
    int v = (s < S) ? cnt[s] : 0;
    int lane = threadIdx.x & 63;
    int wv = threadIdx.x >> 6;
    int sc = v;
    #pragma unroll
    for (int d = 1; d < 64; d <<= 1) {
        int t = __shfl_up(sc, d, 64);
        if (lane >= d) sc += t;
    }
    if (lane == 63) wsum[wv] = sc;
    __syncthreads();
    if (threadIdx.x == 0) {
        int t = 0;
        #pragma unroll
        for (int i = 0; i < 4; ++i) { int w = wsum[i]; wsum[i] = t; t += w; }
        bb = atomicAdd(total, t);
    }
    __syncthreads();
    int excl = bb + wsum[wv] + sc - v;
    if (s < S) { off[s] = excl; cur[s] = excl; }
}

__global__ void scatter_kernel(const int* __restrict__ eslot, int* __restrict__ cur,
                               int* __restrict__ perm, int E) {
    int e = blockIdx.x * blockDim.x + threadIdx.x;
    if (e >= E) return;
    int p = atomicAdd(&cur[eslot[e]], 1);
    perm[p] = e;
}

// Fully-static MFMA + max-fold over NT m-tiles. No runtime predicates anywhere near acc:
// pad rows duplicate a real segment edge, so folding them into the max is EXACT.
template<int NT>
__device__ __forceinline__ void mfma_fold(const unsigned short* __restrict__ a_lds,
                                          const unsigned short* __restrict__ wt2,
                                          int n0, int n1, int l15, int quad,
                                          float& rm0, float& rm1) {
    f32x4 acc[NT][2];
    #pragma unroll
    for (int i = 0; i < NT; ++i) {
        acc[i][0] = (f32x4){0.f, 0.f, 0.f, 0.f};
        acc[i][1] = (f32x4){0.f, 0.f, 0.f, 0.f};
    }
    #pragma unroll
    for (int ks = 0; ks < 3; ++ks) {
        const int ko = ks * 32 + quad * 8;
        short8 bf0 = *(const short8*)(wt2 + (size_t)n0 * LROW2 + ko);
        short8 bf1 = *(const short8*)(wt2 + (size_t)n1 * LROW2 + ko);
        #pragma unroll
        for (int mt = 0; mt < NT; ++mt) {
            short8 af = *(const short8*)(a_lds + (mt * 16 + l15) * LROW2 + ko);
            acc[mt][0] = __builtin_amdgcn_mfma_f32_16x16x32_bf16(af, bf0, acc[mt][0], 0, 0, 0);
            acc[mt][1] = __builtin_amdgcn_mfma_f32_16x16x32_bf16(af, bf1, acc[mt][1], 0, 0, 0);
        }
    }
    #pragma unroll
    for (int mt = 0; mt < NT; ++mt) {
        #pragma unroll
        for (int r = 0; r < 4; ++r) {
            rm0 = fmaxf(rm0, acc[mt][0][r]);
            rm1 = fmaxf(rm1, acc[mt][1][r]);
        }
    }
}

// one block per segment; K=96 MFMA over [x[e0]|ppf]; per-segment x[e1].W1+b added after max
__global__ __launch_bounds__(256, 2)
void seg_kernel(const float* __restrict__ x, const float* __restrict__ pos,
                const float* __restrict__ normal, const unsigned short* __restrict__ wt2,
                const unsigned short* __restrict__ w1, const float* __restrict__ bias,
                const int* __restrict__ edge, const int* __restrict__ idx,
                const int* __restrict__ perm, const int* __restrict__ off,
                const int* __restrict__ cnt, float* __restrict__ out, int E) {
    __shared__ __align__(16) unsigned short a_lds[MT * LROW2];
    __shared__ float x1_lds[F_DIM];
    __shared__ float pn_lds[6];

    const int s    = blockIdx.x;
    const int n    = cnt[s];
    const int tid  = threadIdx.x;
    const int wv   = tid >> 6;
    const int lane = tid & 63;
    const int l15  = lane & 15;
    const int quad = lane >> 4;
    const int n0 = wv * 32 + l15;
    const int n1 = n0 + 16;

    if (n == 0) {                       // empty segment (or non-canonical duplicate slot)
        if (quad == 0) {
            out[(size_t)s * H_DIM + n0] = 0.f;
            out[(size_t)s * H_DIM + n1] = 0.f;
        }
        return;
    }

    const int base = off[s];
    const int node = idx[s];            // n>0 => s is the canonical slot of idx[s]

    if (tid < F_DIM)                x1_lds[tid] = x[(size_t)node * F_DIM + tid];
    else if (tid < F_DIM + 3)       pn_lds[tid - F_DIM] = pos[(size_t)node * 3 + (tid - F_DIM)];
    else if (tid < F_DIM + 6)       pn_lds[tid - F_DIM] = normal[(size_t)node * 3 + (tid - F_DIM - 3)];

    // zero k=68..103 of every A row once (staging only ever writes k 0..67)
    const int m_row = tid >> 2;         // 0..63
    const int p4i   = tid & 3;
    {
        unsigned short* arow = a_lds + m_row * LROW2;
        uint4 z4 = make_uint4(0, 0, 0, 0);
        if (p4i == 0) { *(uint2*)(arow + 68) = make_uint2(0, 0); *(uint4*)(arow + 96) = z4; }
        else          { *(uint4*)(arow + 72 + (p4i - 1) * 8) = z4; }
    }
    __syncthreads();

    // per-segment constant c[h] = bias[h] + x[e1] . W1[:,h]  (bf16 weights, as MFMA would)
    float c0 = bias[n0], c1 = bias[n1];
    {
        const short8* r0 = (const short8*)(w1 + (size_t)n0 * F_DIM);
        const short8* r1 = (const short8*)(w1 + (size_t)n1 * F_DIM);
        #pragma unroll
        for (int kk = 0; kk < 8; ++kk) {
            short8 a0 = r0[kk], a1 = r1[kk];
            #pragma unroll
            for (int j = 0; j < 8; ++j) {
                float xv = x1_lds[kk * 8 + j];
                c0 += xv * bf2f((unsigned short)a0[j]);
                c1 += xv * bf2f((unsigned short)a1[j]);
            }
        }
    }
    const float pe1x = pn_lds[0], pe1y = pn_lds[1], pe1z = pn_lds[2];
    const float ne1x = pn_lds[3], ne1y = pn_lds[4], ne1z = pn_lds[5];

    float rm0 = -FLT_MAX, rm1 = -FLT_MAX;

    for (int cbase = 0; cbase < n; cbase += MT) {
        int valid = n - cbase; if (valid > MT) valid = MT;
        int ntr = (valid <= 32) ? 2 : 4;    // m-tiles this chunk, rounded to a static path

        if (m_row < ntr * 16) {             // stage rows [0, ntr*16); pads clamp to a real edge
            int r = cbase + m_row;
            if (r >= n) r = n - 1;
            int e = perm[base + r];
            int e0 = edge[e];
            unsigned short* arow = a_lds + m_row * LROW2;
            // x[e0] quarter p4i: 16 feats -> 16 bf16
            const float4* s4 = (const float4*)(x + (size_t)e0 * F_DIM + p4i * 16);
            float4 f0 = s4[0], f1 = s4[1], f2 = s4[2], f3 = s4[3];
            uint4 q0, q1;
            q0.x = pk(f0.x, f0.y); q0.y = pk(f0.z, f0.w);
            q0.z = pk(f1.x, f1.y); q0.w = pk(f1.z, f1.w);
            q1.x = pk(f2.x, f2.y); q1.y = pk(f2.z, f2.w);
            q1.z = pk(f3.x, f3.y); q1.w = pk(f3.z, f3.w);
            *(uint4*)(arow + p4i * 16)     = q0;
            *(uint4*)(arow + p4i * 16 + 8) = q1;
            // ppf component p4i for this row
            float px = pos[3 * e0]     - pe1x;
            float py = pos[3 * e0 + 1] - pe1y;
            float pz = pos[3 * e0 + 2] - pe1z;
            float val;
            if (p4i == 0) {
                val = sqrtf(px * px + py * py + pz * pz);
            } else if (p4i == 1) {
                val = angle3(ne1x, ne1y, ne1z, px, py, pz);
            } else {
                float n0x = normal[3 * e0], n0y = normal[3 * e0 + 1], n0z = normal[3 * e0 + 2];
                val = (p4i == 2) ? angle3(n0x, n0y, n0z, px, py, pz)
                                 : angle3(ne1x, ne1y, ne1z, n0x, n0y, n0z);
            }
            arow[F_DIM + p4i] = f2bf(val);
        }
        __syncthreads();

        if (ntr == 2) mfma_fold<2>(a_lds, wt2, n0, n1, l15, quad, rm0, rm1);
        else          mfma_fold<4>(a_lds, wt2, n0, n1, l15, quad, rm0, rm1);

        __syncthreads();                // a_lds reused next chunk
    }

    // cross-quad max, then add constant and relu (relu monotone => hoist exact)
    rm0 = fmaxf(rm0, __shfl_xor(rm0, 16, 64));
    rm0 = fmaxf(rm0, __shfl_xor(rm0, 32, 64));
    rm1 = fmaxf(rm1, __shfl_xor(rm1, 16, 64));
    rm1 = fmaxf(rm1, __shfl_xor(rm1, 32, 64));
    if (quad == 0) {
        out[(size_t)s * H_DIM + n0] = fmaxf(c0 + rm0, 0.f);
        out[(size_t)s * H_DIM + n1] = fmaxf(c1 + rm1, 0.f);
    }
}

// duplicate-idx fixup (non-canonical rows copy from canonical) + pos gather
__global__ void finalize(const int* __restrict__ idx, const int* __restrict__ node2slot,
                         const float* __restrict__ pos, float* __restrict__ out, int S) {
    int g = blockIdx.x * blockDim.x + threadIdx.x;
    int total = S * H_DIM;
    if (g < total) {
        int s = g >> 7, c = g & 127;
        int node = idx[s];
        int sp = node2slot[node];
        if (sp != s) out[g] = out[(size_t)sp * H_DIM + c];
    } else if (g < total + 3 * S) {
        int g2 = g - total;
        int s = g2 / 3, j = g2 - 3 * s;
        out[total + g2] = pos[(size_t)idx[s] * 3 + j];
    }
}

extern "C" void kernel_launch(void* const* d_in, const int* in_sizes, int n_in,
                              void* d_out, int out_size, void* d_ws, size_t ws_size,
                              hipStream_t stream) {
    const float* x      = (const float*)d_in[0];
    const float* pos    = (const float*)d_in[1];
    const float* normal = (const float*)d_in[2];
    const float* W      = (const float*)d_in[3];
    const float* b      = (const float*)d_in[4];
    const int*   edge   = (const int*)d_in[5];
    const int*   idx    = (const int*)d_in[6];

    const int H = in_sizes[4];            // 128
    const int K = in_sizes[3] / H;        // 132
    const int F = (K - 4) / 2;            // 64
    const int N = in_sizes[0] / F;        // 100000
    const int E = in_sizes[5] / 2;        // 800000
    const int S = in_sizes[6];            // 25000

    // ws layout (256B aligned): wt2 | w1 | node2slot[N] | eslot[E] | perm[E] | cnt[S+1] | off[S] | cur[S]
    char* p = (char*)d_ws;
    auto alloc = [&](size_t bytes) { char* r = p; p += (bytes + 255) & ~(size_t)255; return r; };
    unsigned short* wt2 = (unsigned short*)alloc((size_t)H_DIM * LROW2 * sizeof(unsigned short));
    unsigned short* w1  = (unsigned short*)alloc((size_t)H_DIM * F_DIM * sizeof(unsigned short));
    int* node2slot      = (int*)alloc((size_t)N * sizeof(int));
    int* eslot          = (int*)alloc((size_t)E * sizeof(int));
    int* perm           = (int*)alloc((size_t)E * sizeof(int));
    int* cnt            = (int*)alloc((size_t)(S + 1) * sizeof(int));  // cnt[S] = total counter
    int* off            = (int*)alloc((size_t)S * sizeof(int));
    int* cur            = (int*)alloc((size_t)S * sizeof(int));
    float* out = (float*)d_out;

    hipMemsetAsync(cnt, 0, (size_t)(S + 1) * sizeof(int), stream);

    build_w<<<(H_DIM * (LROW2 + F_DIM) + 255) / 256, 256, 0, stream>>>(W, wt2, w1);
    scatter_slots<<<(S + 255) / 256, 256, 0, stream>>>(idx, node2slot, S);
    hist_kernel<<<(E + 255) / 256, 256, 0, stream>>>(edge, node2slot, eslot, cnt, E);
    alloc_kernel<<<(S + 255) / 256, 256, 0, stream>>>(cnt, off, cur, cnt + S, S);
    scatter_kernel<<<(E + 255) / 256, 256, 0, stream>>>(eslot, cur, perm, E);
    seg_kernel<<<S, 256, 0, stream>>>(x, pos, normal, wt2, w1, b, edge, idx, perm, off, cnt, out, E);
    finalize<<<(S * H + 3 * S + 255) / 256, 256, 0, stream>>>(idx, node2slot, pos, out, S);
}

// Round 4
// 308.802 us; speedup vs baseline: 10.7034x; 1.8072x over previous
//
#include <hip/hip_runtime.h>
#include <hip/hip_bf16.h>
#include <float.h>

#define F_DIM 64
#define H_DIM 128
#define LW2   104   // wt2 row stride (bf16) for K=96 [x[e0]|ppf|pad]: 208 B, 16B-aligned
#define LW1   72    // w1t row stride (bf16) for K=64 [x[e1]]: 144 B, 16B-aligned

typedef __attribute__((ext_vector_type(8))) short short8;   // 8 bf16 (mfma A/B frag)
typedef __attribute__((ext_vector_type(4))) float f32x4;    // mfma C/D frag

__device__ __forceinline__ unsigned short f2bf(float f) {
    __hip_bfloat16 h = __float2bfloat16(f);
    return __builtin_bit_cast(unsigned short, h);
}
__device__ __forceinline__ unsigned pk(float a, float b) {
    return (unsigned)f2bf(a) | ((unsigned)f2bf(b) << 16);
}
__device__ __forceinline__ short8 pack_bf8(float4 a, float4 b) {
    short8 r;
    r[0]=(short)f2bf(a.x); r[1]=(short)f2bf(a.y); r[2]=(short)f2bf(a.z); r[3]=(short)f2bf(a.w);
    r[4]=(short)f2bf(b.x); r[5]=(short)f2bf(b.y); r[6]=(short)f2bf(b.z); r[7]=(short)f2bf(b.w);
    return r;
}

__device__ __forceinline__ float angle3(float ax, float ay, float az,
                                        float bx, float by, float bz) {
    float cx = ay*bz - az*by;
    float cy = az*bx - ax*bz;
    float cz = ax*by - ay*bx;
    float cn = sqrtf(cx*cx + cy*cy + cz*cz);
    float d  = ax*bx + ay*by + az*bz;
    return atan2f(cn, d);
}

// fused: wt2 build + w1t build + node2slot scatter + cnt zero (all independent)
__global__ __launch_bounds__(256)
void prep0(const float* __restrict__ W, unsigned short* __restrict__ wt2,
           unsigned short* __restrict__ w1t, const int* __restrict__ idx,
           int* __restrict__ node2slot, int* __restrict__ cnt, int S) {
    const int T = gridDim.x * blockDim.x;
    const int gid = blockIdx.x * blockDim.x + threadIdx.x;
    for (int g = gid; g < H_DIM * LW2; g += T) {          // W rows 64..131 -> [H][LW2]
        int h = g / LW2, k = g % LW2;
        float v = 0.f;
        if (k < F_DIM)          v = W[(F_DIM + k) * H_DIM + h];
        else if (k < F_DIM + 4) v = W[(2 * F_DIM + (k - F_DIM)) * H_DIM + h];
        wt2[g] = f2bf(v);
    }
    for (int g = gid; g < H_DIM * LW1; g += T) {          // W rows 0..63 -> [H][LW1]
        int h = g / LW1, k = g % LW1;
        w1t[g] = f2bf((k < F_DIM) ? W[k * H_DIM + h] : 0.f);
    }
    for (int g = gid; g < S; g += T) node2slot[idx[g]] = g;  // any winner = canonical slot
    for (int g = gid; g <= S; g += T) cnt[g] = 0;            // cnt[S] = total counter
}

__global__ void hist_kernel(const int* __restrict__ edge, const int* __restrict__ node2slot,
                            int* __restrict__ eslot, int* __restrict__ cnt, int E) {
    int e = blockIdx.x * blockDim.x + threadIdx.x;
    if (e >= E) return;
    int s = node2slot[edge[E + e]];     // every e1 is a sampled node -> guaranteed hit
    eslot[e] = s;
    atomicAdd(&cnt[s], 1);
}

// blocks [0,AB): per-slot contiguous range alloc. blocks [AB,AB+CB): cmat = b + x[idx]·W1 -> out
__global__ __launch_bounds__(256)
void alloc_cmat(const int* __restrict__ cnt, int* __restrict__ off, int* __restrict__ cur,
                int* __restrict__ total, const float* __restrict__ x,
                const unsigned short* __restrict__ w1t, const float* __restrict__ bias,
                const int* __restrict__ idx, float* __restrict__ out, int S, int AB) {
    __shared__ int wsum[4];
    __shared__ int bb;
    __shared__ __align__(16) unsigned short a_lds[64 * LW1];
    const int tid = threadIdx.x;

    if ((int)blockIdx.x < AB) {
        int s = blockIdx.x * 256 + tid;
        int v = (s < S) ? cnt[s] : 0;
        int lane = tid & 63, wv = tid >> 6;
        int sc = v;
        #pragma unroll
        for (int d = 1; d < 64; d <<= 1) {
            int t = __shfl_up(sc, d, 64);
            if (lane >= d) sc += t;
        }
        if (lane == 63) wsum[wv] = sc;
        __syncthreads();
        if (tid == 0) {
            int t = 0;
            #pragma unroll
            for (int i = 0; i < 4; ++i) { int w = wsum[i]; wsum[i] = t; t += w; }
            bb = atomicAdd(total, t);
        }
        __syncthreads();
        int excl = bb + wsum[wv] + sc - v;
        if (s < S) { off[s] = excl; cur[s] = excl; }
        return;
    }

    // ---- cmat: 64 slots per block ----
    const int sbase = (blockIdx.x - AB) * 64;
    const int m = tid >> 2, p = tid & 3;
    {
        int s = sbase + m; if (s >= S) s = S - 1;
        int node = idx[s];
        const float4* s4 = (const float4*)(x + (size_t)node * F_DIM + p * 16);
        float4 f0 = s4[0], f1 = s4[1], f2 = s4[2], f3 = s4[3];
        uint4 q0, q1;
        q0.x = pk(f0.x, f0.y); q0.y = pk(f0.z, f0.w);
        q0.z = pk(f1.x, f1.y); q0.w = pk(f1.z, f1.w);
        q1.x = pk(f2.x, f2.y); q1.y = pk(f2.z, f2.w);
        q1.z = pk(f3.x, f3.y); q1.w = pk(f3.z, f3.w);
        uint4* dst = (uint4*)(a_lds + m * LW1 + p * 16);
        dst[0] = q0; dst[1] = q1;
        if (p == 0) *(uint4*)(a_lds + m * LW1 + 64) = make_uint4(0, 0, 0, 0);
    }
    __syncthreads();
    const int wv = tid >> 6, lane = tid & 63, l15 = lane & 15, quad = lane >> 4;
    const int n0 = wv * 32 + l15, n1 = n0 + 16;
    f32x4 acc[4][2];
    #pragma unroll
    for (int i = 0; i < 4; ++i) {
        acc[i][0] = (f32x4){0.f, 0.f, 0.f, 0.f};
        acc[i][1] = (f32x4){0.f, 0.f, 0.f, 0.f};
    }
    #pragma unroll
    for (int ks = 0; ks < 2; ++ks) {
        const int ko = ks * 32 + quad * 8;
        short8 bf0 = *(const short8*)(w1t + (size_t)n0 * LW1 + ko);
        short8 bf1 = *(const short8*)(w1t + (size_t)n1 * LW1 + ko);
        #pragma unroll
        for (int mt = 0; mt < 4; ++mt) {
            short8 af = *(const short8*)(a_lds + (mt * 16 + l15) * LW1 + ko);
            acc[mt][0] = __builtin_amdgcn_mfma_f32_16x16x32_bf16(af, bf0, acc[mt][0], 0, 0, 0);
            acc[mt][1] = __builtin_amdgcn_mfma_f32_16x16x32_bf16(af, bf1, acc[mt][1], 0, 0, 0);
        }
    }
    const float b0 = bias[n0], b1 = bias[n1];
    #pragma unroll
    for (int mt = 0; mt < 4; ++mt) {
        #pragma unroll
        for (int r = 0; r < 4; ++r) {
            int s = sbase + mt * 16 + quad * 4 + r;     // C/D: row = quad*4 + reg
            if (s < S) {
                out[(size_t)s * H_DIM + n0] = acc[mt][0][r] + b0;
                out[(size_t)s * H_DIM + n1] = acc[mt][1][r] + b1;
            }
        }
    }
}

__global__ void scatter_kernel(const int* __restrict__ edge, const int* __restrict__ eslot,
                               int* __restrict__ cur, int* __restrict__ perm, int E) {
    int e = blockIdx.x * blockDim.x + threadIdx.x;
    if (e >= E) return;
    int p = atomicAdd(&cur[eslot[e]], 1);
    perm[p] = edge[e];                  // store e0 node id directly (one less gather level)
}

// wave-per-segment: A-frags direct from global, W2 in LDS (staged once/block), no barriers
// in the segment loop. out row = relu(c + max), RMW in place (c written by cmat).
__global__ __launch_bounds__(256, 2)
void seg_kernel(const float* __restrict__ x, const float* __restrict__ pos,
                const float* __restrict__ normal, const unsigned short* __restrict__ wt2,
                const int* __restrict__ idx, const int* __restrict__ perm,
                const int* __restrict__ off, const int* __restrict__ cnt,
                float* __restrict__ out, int S) {
    __shared__ __align__(16) unsigned short w_lds[H_DIM * LW2];
    {
        const uint4* src = (const uint4*)wt2;
        uint4* dst = (uint4*)w_lds;
        for (int g = threadIdx.x; g < H_DIM * LW2 / 8; g += 256) dst[g] = src[g];
    }
    __syncthreads();

    const int tid  = threadIdx.x;
    const int wv   = tid >> 6;
    const int lane = tid & 63;
    const int l15  = lane & 15;
    const int quad = lane >> 4;
    const int nw   = gridDim.x << 2;

    for (int s = (blockIdx.x << 2) + wv; s < S; s += nw) {
        const int n = cnt[s];
        float* orow = out + (size_t)s * H_DIM;
        if (n == 0) {                   // empty segment or non-canonical duplicate slot
            orow[lane] = 0.f;
            orow[64 + lane] = 0.f;
            continue;
        }
        const int base = off[s];
        const int node = idx[s];
        const float pe1x = pos[(size_t)node * 3],    pe1y = pos[(size_t)node * 3 + 1],
                    pe1z = pos[(size_t)node * 3 + 2];
        const float ne1x = normal[(size_t)node * 3], ne1y = normal[(size_t)node * 3 + 1],
                    ne1z = normal[(size_t)node * 3 + 2];

        float rm[8];
        #pragma unroll
        for (int ct = 0; ct < 8; ++ct) rm[ct] = -FLT_MAX;

        const int ntile = (n + 15) >> 4;
        for (int t = 0; t < ntile; ++t) {
            int r = (t << 4) + l15;
            if (r >= n) r = n - 1;      // pad rows duplicate a real edge -> exact for max
            const int e0 = perm[base + r];
            const float* xr = x + (size_t)e0 * F_DIM;
            const float4* xq0 = (const float4*)(xr + quad * 8);
            const float4* xq1 = (const float4*)(xr + 32 + quad * 8);
            float4 xa = xq0[0], xb = xq0[1];
            float4 xc = xq1[0], xd = xq1[1];
            short8 af0 = pack_bf8(xa, xb);      // k = quad*8 .. +8
            short8 af1 = pack_bf8(xc, xd);      // k = 32 + quad*8 .. +8

            // ppf: each lane computes component `quad` of row l15; gather via shfl_xor
            float px = pos[(size_t)e0 * 3]     - pe1x;
            float py = pos[(size_t)e0 * 3 + 1] - pe1y;
            float pz = pos[(size_t)e0 * 3 + 2] - pe1z;
            float val;
            if (quad == 0) {
                val = sqrtf(px * px + py * py + pz * pz);
            } else if (quad == 1) {
                val = angle3(ne1x, ne1y, ne1z, px, py, pz);
            } else {
                float n0x = normal[(size_t)e0 * 3],     n0y = normal[(size_t)e0 * 3 + 1],
                      n0z = normal[(size_t)e0 * 3 + 2];
                val = (quad == 2) ? angle3(n0x, n0y, n0z, px, py, pz)
                                  : angle3(ne1x, ne1y, ne1z, n0x, n0y, n0z);
            }
            float pf1 = __shfl_xor(val, 16, 64);
            float pf2 = __shfl_xor(val, 32, 64);
            float pf3 = __shfl_xor(val, 48, 64);
            short8 af2 = (short8){0, 0, 0, 0, 0, 0, 0, 0};
            if (quad == 0) {            // k = 64..67 = ppf; 68..71 zero (B zero past 67 anyway)
                af2[0] = (short)f2bf(val); af2[1] = (short)f2bf(pf1);
                af2[2] = (short)f2bf(pf2); af2[3] = (short)f2bf(pf3);
            }

            f32x4 acc[8];
            #pragma unroll
            for (int ct = 0; ct < 8; ++ct) acc[ct] = (f32x4){0.f, 0.f, 0.f, 0.f};
            #pragma unroll
            for (int ct = 0; ct < 8; ++ct) {
                const unsigned short* wc = w_lds + (ct * 16 + l15) * LW2 + (quad << 3);
                short8 b0 = *(const short8*)(wc);
                short8 b1 = *(const short8*)(wc + 32);
                short8 b2 = *(const short8*)(wc + 64);
                acc[ct] = __builtin_amdgcn_mfma_f32_16x16x32_bf16(af0, b0, acc[ct], 0, 0, 0);
                acc[ct] = __builtin_amdgcn_mfma_f32_16x16x32_bf16(af1, b1, acc[ct], 0, 0, 0);
                acc[ct] = __builtin_amdgcn_mfma_f32_16x16x32_bf16(af2, b2, acc[ct], 0, 0, 0);
            }
            #pragma unroll
            for (int ct = 0; ct < 8; ++ct)
                rm[ct] = fmaxf(rm[ct], fmaxf(fmaxf(acc[ct][0], acc[ct][1]),
                                             fmaxf(acc[ct][2], acc[ct][3])));
        }

        #pragma unroll
        for (int ct = 0; ct < 8; ++ct) {
            rm[ct] = fmaxf(rm[ct], __shfl_xor(rm[ct], 16, 64));
            rm[ct] = fmaxf(rm[ct], __shfl_xor(rm[ct], 32, 64));
        }
        float v0 = rm[0], v1 = rm[4];   // col = ct*16 + l15; lane writes cols lane, lane+64
        if (quad == 1)      { v0 = rm[1]; v1 = rm[5]; }
        else if (quad == 2) { v0 = rm[2]; v1 = rm[6]; }
        else if (quad == 3) { v0 = rm[3]; v1 = rm[7]; }
        orow[lane]      = fmaxf(orow[lane] + v0, 0.f);        // c + max, relu (hoist exact)
        orow[64 + lane] = fmaxf(orow[64 + lane] + v1, 0.f);
    }
}

// duplicate-idx fixup (non-canonical rows copy from canonical) + pos gather
__global__ void finalize(const int* __restrict__ idx, const int* __restrict__ node2slot,
                         const float* __restrict__ pos, float* __restrict__ out, int S) {
    int g = blockIdx.x * blockDim.x + threadIdx.x;
    int total = S * H_DIM;
    if (g < total) {
        int s = g >> 7, c = g & 127;
        int node = idx[s];
        int sp = node2slot[node];
        if (sp != s) out[g] = out[(size_t)sp * H_DIM + c];
    } else if (g < total + 3 * S) {
        int g2 = g - total;
        int s = g2 / 3, j = g2 - 3 * s;
        out[total + g2] = pos[(size_t)idx[s] * 3 + j];
    }
}

extern "C" void kernel_launch(void* const* d_in, const int* in_sizes, int n_in,
                              void* d_out, int out_size, void* d_ws, size_t ws_size,
                              hipStream_t stream) {
    const float* x      = (const float*)d_in[0];
    const float* pos    = (const float*)d_in[1];
    const float* normal = (const float*)d_in[2];
    const float* W      = (const float*)d_in[3];
    const float* b      = (const float*)d_in[4];
    const int*   edge   = (const int*)d_in[5];
    const int*   idx    = (const int*)d_in[6];

    const int H = in_sizes[4];            // 128
    const int K = in_sizes[3] / H;        // 132
    const int F = (K - 4) / 2;            // 64
    const int N = in_sizes[0] / F;        // 100000
    const int E = in_sizes[5] / 2;        // 800000
    const int S = in_sizes[6];            // 25000

    // ws (256B aligned): wt2 | w1t | node2slot[N] | eslot[E] | perm[E] | cnt[S+1] | off[S] | cur[S]
    char* p = (char*)d_ws;
    auto alloc = [&](size_t bytes) { char* r = p; p += (bytes + 255) & ~(size_t)255; return r; };
    unsigned short* wt2 = (unsigned short*)alloc((size_t)H_DIM * LW2 * sizeof(unsigned short));
    unsigned short* w1t = (unsigned short*)alloc((size_t)H_DIM * LW1 * sizeof(unsigned short));
    int* node2slot      = (int*)alloc((size_t)N * sizeof(int));
    int* eslot          = (int*)alloc((size_t)E * sizeof(int));
    int* perm           = (int*)alloc((size_t)E * sizeof(int));
    int* cnt            = (int*)alloc((size_t)(S + 1) * sizeof(int));
    int* off            = (int*)alloc((size_t)S * sizeof(int));
    int* cur            = (int*)alloc((size_t)S * sizeof(int));
    float* out = (float*)d_out;           // first S*H floats: cmat writes c, seg RMWs to result

    const int AB = (S + 255) / 256;
    const int CB = (S + 63) / 64;

    prep0<<<512, 256, 0, stream>>>(W, wt2, w1t, idx, node2slot, cnt, S);
    hist_kernel<<<(E + 255) / 256, 256, 0, stream>>>(edge, node2slot, eslot, cnt, E);
    alloc_cmat<<<AB + CB, 256, 0, stream>>>(cnt, off, cur, cnt + S, x, w1t, b, idx, out, S, AB);
    scatter_kernel<<<(E + 255) / 256, 256, 0, stream>>>(edge, eslot, cur, perm, E);
    seg_kernel<<<2048, 256, 0, stream>>>(x, pos, normal, wt2, idx, perm, off, cnt, out, S);
    finalize<<<(S * H + 3 * S + 255) / 256, 256, 0, stream>>>(idx, node2slot, pos, out, S);
}

// Round 5
// 244.774 us; speedup vs baseline: 13.5032x; 1.2616x over previous
//
#include <hip/hip_runtime.h>
#include <hip/hip_bf16.h>
#include <float.h>

#define F_DIM 64
#define H_DIM 128
#define LW2   104   // wt2 row stride (bf16) for K=96 [x[e0]|ppf|pad]: 208 B, 16B-aligned
#define LW1   72    // w1t row stride (bf16) for K=64 [x[e1]]: 144 B, 16B-aligned

typedef __attribute__((ext_vector_type(8))) short short8;   // 8 bf16 (mfma A/B frag)
typedef __attribute__((ext_vector_type(4))) float f32x4;    // mfma C/D frag

__device__ __forceinline__ unsigned short f2bf(float f) {
    __hip_bfloat16 h = __float2bfloat16(f);
    return __builtin_bit_cast(unsigned short, h);
}
__device__ __forceinline__ unsigned pk(float a, float b) {
    return (unsigned)f2bf(a) | ((unsigned)f2bf(b) << 16);
}

__device__ __forceinline__ float angle3(float ax, float ay, float az,
                                        float bx, float by, float bz) {
    float cx = ay*bz - az*by;
    float cy = az*bx - ax*bz;
    float cz = ax*by - ay*bx;
    float cn = sqrtf(cx*cx + cy*cy + cz*cz);
    float d  = ax*bx + ay*by + az*bz;
    return atan2f(cn, d);
}

// fused streaming pass: wt2 + w1t builds, xbf (x -> bf16, mfma-frag layout), node2slot,
// cnt zero, pos-gather part of the output (independent of everything else)
__global__ __launch_bounds__(256)
void prep0(const float* __restrict__ W, unsigned short* __restrict__ wt2,
           unsigned short* __restrict__ w1t, const float* __restrict__ x,
           unsigned short* __restrict__ xbf, const int* __restrict__ idx,
           int* __restrict__ node2slot, int* __restrict__ cnt,
           const float* __restrict__ pos, float* __restrict__ out, int S, int NF8) {
    const int T = gridDim.x * blockDim.x;
    const int gid = blockIdx.x * blockDim.x + threadIdx.x;
    for (int g = gid; g < NF8; g += T) {                  // x[N][64] f32 -> bf16, 8/thread
        const float4* s4 = (const float4*)x + (size_t)g * 2;
        float4 f0 = s4[0], f1 = s4[1];
        uint4 q;
        q.x = pk(f0.x, f0.y); q.y = pk(f0.z, f0.w);
        q.z = pk(f1.x, f1.y); q.w = pk(f1.z, f1.w);
        ((uint4*)xbf)[g] = q;
    }
    for (int g = gid; g < H_DIM * LW2; g += T) {          // W rows 64..131 -> [H][LW2]
        int h = g / LW2, k = g % LW2;
        float v = 0.f;
        if (k < F_DIM)          v = W[(F_DIM + k) * H_DIM + h];
        else if (k < F_DIM + 4) v = W[(2 * F_DIM + (k - F_DIM)) * H_DIM + h];
        wt2[g] = f2bf(v);
    }
    for (int g = gid; g < H_DIM * LW1; g += T) {          // W rows 0..63 -> [H][LW1]
        int h = g / LW1, k = g % LW1;
        w1t[g] = f2bf((k < F_DIM) ? W[k * H_DIM + h] : 0.f);
    }
    for (int g = gid; g < S; g += T) node2slot[idx[g]] = g;  // any winner = canonical slot
    for (int g = gid; g <= S; g += T) cnt[g] = 0;            // cnt[S] = total counter
    for (int g = gid; g < 3 * S; g += T)                     // out tail = pos[idx]
        out[(size_t)S * H_DIM + g] = pos[(size_t)idx[g / 3] * 3 + (g % 3)];
}

__global__ void hist_kernel(const int* __restrict__ edge, const int* __restrict__ node2slot,
                            int* __restrict__ eslot, int* __restrict__ cnt, int E) {
    int e = blockIdx.x * blockDim.x + threadIdx.x;
    if (e >= E) return;
    int s = node2slot[edge[E + e]];     // every e1 is a sampled node -> guaranteed hit
    eslot[e] = s;
    atomicAdd(&cnt[s], 1);
}

// blocks [0,AB): per-slot contiguous range alloc. blocks [AB,AB+CB): cmat = b + x[idx]·W1 -> out
__global__ __launch_bounds__(256)
void alloc_cmat(const int* __restrict__ cnt, int* __restrict__ off, int* __restrict__ cur,
                int* __restrict__ total, const unsigned short* __restrict__ xbf,
                const unsigned short* __restrict__ w1t, const float* __restrict__ bias,
                const int* __restrict__ idx, float* __restrict__ out, int S, int AB) {
    __shared__ int wsum[4];
    __shared__ int bb;
    __shared__ __align__(16) unsigned short a_lds[64 * LW1];
    const int tid = threadIdx.x;

    if ((int)blockIdx.x < AB) {
        int s = blockIdx.x * 256 + tid;
        int v = (s < S) ? cnt[s] : 0;
        int lane = tid & 63, wv = tid >> 6;
        int sc = v;
        #pragma unroll
        for (int d = 1; d < 64; d <<= 1) {
            int t = __shfl_up(sc, d, 64);
            if (lane >= d) sc += t;
        }
        if (lane == 63) wsum[wv] = sc;
        __syncthreads();
        if (tid == 0) {
            int t = 0;
            #pragma unroll
            for (int i = 0; i < 4; ++i) { int w = wsum[i]; wsum[i] = t; t += w; }
            bb = atomicAdd(total, t);
        }
        __syncthreads();
        int excl = bb + wsum[wv] + sc - v;
        if (s < S) { off[s] = excl; cur[s] = excl; }
        return;
    }

    // ---- cmat: 64 slots per block, A rows from xbf (already bf16) ----
    const int sbase = (blockIdx.x - AB) * 64;
    const int m = tid >> 2, p = tid & 3;
    {
        int s = sbase + m; if (s >= S) s = S - 1;
        int node = idx[s];
        const uint4* src = (const uint4*)(xbf + (size_t)node * F_DIM) + p * 2;
        uint4* dst = (uint4*)(a_lds + m * LW1 + p * 16);
        dst[0] = src[0]; dst[1] = src[1];
        if (p == 0) *(uint4*)(a_lds + m * LW1 + 64) = make_uint4(0, 0, 0, 0);
    }
    __syncthreads();
    const int wv = tid >> 6, lane = tid & 63, l15 = lane & 15, quad = lane >> 4;
    const int n0 = wv * 32 + l15, n1 = n0 + 16;
    f32x4 acc[4][2];
    #pragma unroll
    for (int i = 0; i < 4; ++i) {
        acc[i][0] = (f32x4){0.f, 0.f, 0.f, 0.f};
        acc[i][1] = (f32x4){0.f, 0.f, 0.f, 0.f};
    }
    #pragma unroll
    for (int ks = 0; ks < 2; ++ks) {
        const int ko = ks * 32 + quad * 8;
        short8 bf0 = *(const short8*)(w1t + (size_t)n0 * LW1 + ko);
        short8 bf1 = *(const short8*)(w1t + (size_t)n1 * LW1 + ko);
        #pragma unroll
        for (int mt = 0; mt < 4; ++mt) {
            short8 af = *(const short8*)(a_lds + (mt * 16 + l15) * LW1 + ko);
            acc[mt][0] = __builtin_amdgcn_mfma_f32_16x16x32_bf16(af, bf0, acc[mt][0], 0, 0, 0);
            acc[mt][1] = __builtin_amdgcn_mfma_f32_16x16x32_bf16(af, bf1, acc[mt][1], 0, 0, 0);
        }
    }
    const float b0 = bias[n0], b1 = bias[n1];
    #pragma unroll
    for (int mt = 0; mt < 4; ++mt) {
        #pragma unroll
        for (int r = 0; r < 4; ++r) {
            int s = sbase + mt * 16 + quad * 4 + r;     // C/D: row = quad*4 + reg
            if (s < S) {
                out[(size_t)s * H_DIM + n0] = acc[mt][0][r] + b0;
                out[(size_t)s * H_DIM + n1] = acc[mt][1][r] + b1;
            }
        }
    }
}

// place edges + precompute ppf into a 16-B record per perm position: {e0, pk(d,a1), pk(a2,a3), 0}
// runs at full occupancy -> gather+trig latency hidden here, off seg's critical chain
__global__ void scatter_kernel(const int* __restrict__ edge, const float* __restrict__ pos,
                               const float* __restrict__ normal, const int* __restrict__ eslot,
                               int* __restrict__ cur, uint4* __restrict__ prec, int E) {
    int e = blockIdx.x * blockDim.x + threadIdx.x;
    if (e >= E) return;
    int p = atomicAdd(&cur[eslot[e]], 1);
    int e0 = edge[e], e1 = edge[E + e];
    float px = pos[3 * e0]     - pos[3 * e1];
    float py = pos[3 * e0 + 1] - pos[3 * e1 + 1];
    float pz = pos[3 * e0 + 2] - pos[3 * e1 + 2];
    float n0x = normal[3 * e0], n0y = normal[3 * e0 + 1], n0z = normal[3 * e0 + 2];
    float n1x = normal[3 * e1], n1y = normal[3 * e1 + 1], n1z = normal[3 * e1 + 2];
    float d  = sqrtf(px * px + py * py + pz * pz);
    float a1 = angle3(n1x, n1y, n1z, px, py, pz);
    float a2 = angle3(n0x, n0y, n0z, px, py, pz);
    float a3 = angle3(n1x, n1y, n1z, n0x, n0y, n0z);
    uint4 rec;
    rec.x = (unsigned)e0;
    rec.y = pk(d, a1);
    rec.z = pk(a2, a3);
    rec.w = 0;
    prec[p] = rec;
}

__device__ __forceinline__ void load_af(uint4 rec, const unsigned short* __restrict__ xbf,
                                        int quad, short8& a0, short8& a1, short8& a2) {
    const short8* xr = (const short8*)(xbf + (size_t)rec.x * F_DIM);
    a0 = xr[quad];          // k = quad*8 .. +8
    a1 = xr[4 + quad];      // k = 32 + quad*8 .. +8
    short8 z = (short8){0, 0, 0, 0, 0, 0, 0, 0};
    if (quad == 0) {        // k = 64..67 = ppf, 68..71 zero (wt2 rows 68+ are zero anyway)
        z[0] = (short)(rec.y & 0xffff); z[1] = (short)(rec.y >> 16);
        z[2] = (short)(rec.z & 0xffff); z[3] = (short)(rec.z >> 16);
    }
    a2 = z;
}

// wave-per-segment: A from prec/xbf (no conversion, no trig), W2 in LDS staged once/block,
// software-pipelined tile loop, out row = relu(c + max) RMW (c written by cmat)
__global__ __launch_bounds__(256, 2)
void seg_kernel(const unsigned short* __restrict__ xbf, const unsigned short* __restrict__ wt2,
                const uint4* __restrict__ prec, const int* __restrict__ off,
                const int* __restrict__ cnt, float* __restrict__ out, int S) {
    __shared__ __align__(16) unsigned short w_lds[H_DIM * LW2];
    {
        const uint4* src = (const uint4*)wt2;
        uint4* dst = (uint4*)w_lds;
        for (int g = threadIdx.x; g < H_DIM * LW2 / 8; g += 256) dst[g] = src[g];
    }
    __syncthreads();

    const int tid  = threadIdx.x;
    const int wv   = tid >> 6;
    const int lane = tid & 63;
    const int l15  = lane & 15;
    const int quad = lane >> 4;
    const int nw   = gridDim.x << 2;

    for (int s = (blockIdx.x << 2) + wv; s < S; s += nw) {
        const int n = cnt[s];
        float* orow = out + (size_t)s * H_DIM;
        if (n == 0) {                   // empty segment or non-canonical duplicate slot
            orow[lane] = 0.f;
            orow[64 + lane] = 0.f;
            continue;
        }
        const uint4* pb = prec + off[s];

        float rm[8];
        #pragma unroll
        for (int ct = 0; ct < 8; ++ct) rm[ct] = -FLT_MAX;

        const int ntile = (n + 15) >> 4;
        int r = l15; if (r >= n) r = n - 1;           // pad rows = real edge dup -> exact for max
        uint4 rec = pb[r];
        short8 a0c, a1c, a2c;
        load_af(rec, xbf, quad, a0c, a1c, a2c);

        for (int t = 0; t < ntile; ++t) {
            // prefetch next tile's record + A-frags (overlaps the MFMAs below)
            uint4 recn = rec;
            if (t + 1 < ntile) {
                int rn = ((t + 1) << 4) + l15; if (rn >= n) rn = n - 1;
                recn = pb[rn];
            }
            short8 a0n, a1n, a2n;
            load_af(recn, xbf, quad, a0n, a1n, a2n);

            f32x4 acc[8];
            #pragma unroll
            for (int ct = 0; ct < 8; ++ct) acc[ct] = (f32x4){0.f, 0.f, 0.f, 0.f};
            #pragma unroll
            for (int ct = 0; ct < 8; ++ct) {
                const unsigned short* wc = w_lds + (ct * 16 + l15) * LW2 + (quad << 3);
                short8 b0 = *(const short8*)(wc);
                short8 b1 = *(const short8*)(wc + 32);
                short8 b2 = *(const short8*)(wc + 64);
                acc[ct] = __builtin_amdgcn_mfma_f32_16x16x32_bf16(a0c, b0, acc[ct], 0, 0, 0);
                acc[ct] = __builtin_amdgcn_mfma_f32_16x16x32_bf16(a1c, b1, acc[ct], 0, 0, 0);
                acc[ct] = __builtin_amdgcn_mfma_f32_16x16x32_bf16(a2c, b2, acc[ct], 0, 0, 0);
            }
            #pragma unroll
            for (int ct = 0; ct < 8; ++ct)
                rm[ct] = fmaxf(rm[ct], fmaxf(fmaxf(acc[ct][0], acc[ct][1]),
                                             fmaxf(acc[ct][2], acc[ct][3])));
            a0c = a0n; a1c = a1n; a2c = a2n; rec = recn;
        }

        #pragma unroll
        for (int ct = 0; ct < 8; ++ct) {
            rm[ct] = fmaxf(rm[ct], __shfl_xor(rm[ct], 16, 64));
            rm[ct] = fmaxf(rm[ct], __shfl_xor(rm[ct], 32, 64));
        }
        float v0 = rm[0], v1 = rm[4];   // col = ct*16 + l15; lane writes cols lane, lane+64
        if (quad == 1)      { v0 = rm[1]; v1 = rm[5]; }
        else if (quad == 2) { v0 = rm[2]; v1 = rm[6]; }
        else if (quad == 3) { v0 = rm[3]; v1 = rm[7]; }
        orow[lane]      = fmaxf(orow[lane] + v0, 0.f);        // c + max, relu (hoist exact)
        orow[64 + lane] = fmaxf(orow[64 + lane] + v1, 0.f);
    }
}

// duplicate-idx fixup only (pos tail handled by prep0)
__global__ void finalize(const int* __restrict__ idx, const int* __restrict__ node2slot,
                         float* __restrict__ out, int S) {
    int g = blockIdx.x * blockDim.x + threadIdx.x;
    if (g >= S * H_DIM) return;
    int s = g >> 7, c = g & 127;
    int sp = node2slot[idx[s]];
    if (sp != s) out[g] = out[(size_t)sp * H_DIM + c];
}

extern "C" void kernel_launch(void* const* d_in, const int* in_sizes, int n_in,
                              void* d_out, int out_size, void* d_ws, size_t ws_size,
                              hipStream_t stream) {
    const float* x      = (const float*)d_in[0];
    const float* pos    = (const float*)d_in[1];
    const float* normal = (const float*)d_in[2];
    const float* W      = (const float*)d_in[3];
    const float* b      = (const float*)d_in[4];
    const int*   edge   = (const int*)d_in[5];
    const int*   idx    = (const int*)d_in[6];

    const int H = in_sizes[4];            // 128
    const int K = in_sizes[3] / H;        // 132
    const int F = (K - 4) / 2;            // 64
    const int N = in_sizes[0] / F;        // 100000
    const int E = in_sizes[5] / 2;        // 800000
    const int S = in_sizes[6];            // 25000

    // ws (256B aligned): wt2 | w1t | xbf[N][64]bf16 | prec[E]uint4 | node2slot[N] | eslot[E]
    //                    | cnt[S+1] | off[S] | cur[S]   (~30 MB total)
    char* p = (char*)d_ws;
    auto alloc = [&](size_t bytes) { char* r = p; p += (bytes + 255) & ~(size_t)255; return r; };
    unsigned short* wt2 = (unsigned short*)alloc((size_t)H_DIM * LW2 * sizeof(unsigned short));
    unsigned short* w1t = (unsigned short*)alloc((size_t)H_DIM * LW1 * sizeof(unsigned short));
    unsigned short* xbf = (unsigned short*)alloc((size_t)N * F_DIM * sizeof(unsigned short));
    uint4* prec         = (uint4*)alloc((size_t)E * sizeof(uint4));
    int* node2slot      = (int*)alloc((size_t)N * sizeof(int));
    int* eslot          = (int*)alloc((size_t)E * sizeof(int));
    int* cnt            = (int*)alloc((size_t)(S + 1) * sizeof(int));
    int* off            = (int*)alloc((size_t)S * sizeof(int));
    int* cur            = (int*)alloc((size_t)S * sizeof(int));
    float* out = (float*)d_out;           // cmat writes c, seg RMWs to final result

    const int AB = (S + 255) / 256;
    const int CB = (S + 63) / 64;
    const int NF8 = N * F_DIM / 8;

    prep0<<<1024, 256, 0, stream>>>(W, wt2, w1t, x, xbf, idx, node2slot, cnt, pos, out, S, NF8);
    hist_kernel<<<(E + 255) / 256, 256, 0, stream>>>(edge, node2slot, eslot, cnt, E);
    alloc_cmat<<<AB + CB, 256, 0, stream>>>(cnt, off, cur, cnt + S, xbf, w1t, b, idx, out, S, AB);
    scatter_kernel<<<(E + 255) / 256, 256, 0, stream>>>(edge, pos, normal, eslot, cur, prec, E);
    seg_kernel<<<2048, 256, 0, stream>>>(xbf, wt2, prec, off, cnt, out, S);
    finalize<<<(S * H + 255) / 256, 256, 0, stream>>>(idx, node2slot, out, S);
}